// Round 13
// baseline (113.402 us; speedup 1.0000x reference)
//
#include <hip/hip_runtime.h>
#include <hip/hip_bf16.h>

#define N_NODES 8192
#define IN_FEAT 128
#define OUT_FEAT 64
#define NEG_SLOPE 0.2f
#define TILES (N_NODES / 16)       // 512 row tiles of 16 -> grid, 4 blocks/CU
#define SUBC 256                   // cols per sub-chunk (staged unit)
#define NSUB (N_NODES / SUBC)      // 32 rounds
#define KPW 2                      // k-steps per consumer wave per round (8/4)
#define ROWPAD 272                 // LDS byte stride per packed row (256+16)
#define BUFSZ (16 * ROWPAD)        // one adj-byte buffer (4352 B)
#define LOG2E 1.44269504088896340736f

using f32x4  = __attribute__((ext_vector_type(4))) float;
using i32x4  = __attribute__((ext_vector_type(4))) int;
using bf16x8 = __attribute__((ext_vector_type(8))) short;

// float -> bf16 bits RNE (k_wh pack, not hot)
static __device__ __forceinline__ short f2bf(float f) {
    unsigned int u = __float_as_uint(f);
    unsigned int r = (u + 0x7FFFu + ((u >> 16) & 1u)) >> 16;
    return (short)r;
}

// hot-path convert: pairs into v_cvt_pk_bf16_f32
static __device__ __forceinline__ short f2bf_fast(float f) {
    __hip_bfloat16 h = __float2bfloat16(f);
    return __builtin_bit_cast(short, h);
}

static __device__ __forceinline__ float exp2_fast(float x) {
    return __builtin_amdgcn_exp2f(x);
}

// ---------------------------------------------------------------------------
// K1: Wh = x @ W (fp32); s1/s2 = (Wh@a1/a2)*log2e; Wh packed bf16 into MFMA
// B-fragment layout: whb[((jb*4+fg)*64 + gl*16+cl)*8 + e]
//   = bf16(Wh[jb*32 + gl*8 + e][fg*16 + cl])
// ---------------------------------------------------------------------------
__global__ __launch_bounds__(256) void k_wh(
    const float* __restrict__ x, const float* __restrict__ W,
    const float* __restrict__ a,
    float* __restrict__ s1, float* __restrict__ s2,
    unsigned short* __restrict__ whb)
{
    __shared__ float xs[4][IN_FEAT];
    const int wv   = threadIdx.x >> 6;
    const int lane = threadIdx.x & 63;
    const int row  = blockIdx.x * 4 + wv;

    const float2 xv = *(const float2*)(x + (size_t)row * IN_FEAT + lane * 2);
    xs[wv][lane * 2]     = xv.x;
    xs[wv][lane * 2 + 1] = xv.y;
    __syncthreads();

    float acc = 0.f;
    #pragma unroll
    for (int k = 0; k < IN_FEAT; ++k)
        acc = fmaf(xs[wv][k], W[k * OUT_FEAT + lane], acc);

    float p1 = acc * a[lane];
    float p2 = acc * a[OUT_FEAT + lane];
    #pragma unroll
    for (int off = 32; off; off >>= 1) {
        p1 += __shfl_xor(p1, off);
        p2 += __shfl_xor(p2, off);
    }
    if (lane == 0) {
        s1[row] = p1 * LOG2E;
        s2[row] = p2 * LOG2E;
    }

    const int jb = row >> 5;
    const int ri = row & 31;
    const int gl = ri >> 3;
    const int e  = ri & 7;
    const int fg = lane >> 4;
    const int cl = lane & 15;
    whb[(((size_t)(jb * 4 + fg) * 64) + (gl * 16 + cl)) * 8 + e] = (unsigned short)f2bf(acc);
}

// ---------------------------------------------------------------------------
// K2 (fused, producer/consumer, 4 blocks/CU = 16 streaming waves/CU):
// waves 0-3 stream adj (1KB/instr plain loads, 2-deep reg ring); waves 4-7
// compute (vmcnt chain = L2-hot whb + s2 only). No s2 LDS stage (keeps LDS
// at 25KB so 4 blocks fit); s2 is 32KB total and L2-resident.
// __launch_bounds__(512,8): 64-VGPR cap -> consumer loads B-fragments 2+2.
// A-fragment: A[m][k], m=lane&15, k=8*(lane>>4)+e.
// ---------------------------------------------------------------------------
__global__ __launch_bounds__(512, 8) void k_fused(
    const int* __restrict__ adj, const float* __restrict__ s1v,
    const float* __restrict__ s2v, const unsigned short* __restrict__ whb,
    float* __restrict__ out)
{
    __shared__ __align__(16) char lds[2 * BUFSZ + 16384 + 256];
    char*  bufs = lds;                                   // 2 x 4352 adj-byte bufs
    float* red  = (float*)(lds + 2 * BUFSZ);             // 4096 floats (16 KB)
    float* zl   = (float*)(lds + 2 * BUFSZ + 16384);     // 64 floats

    const int tid  = threadIdx.x;
    const int lane = tid & 63;
    const int w    = tid >> 6;                           // 0..7
    const int tile = blockIdx.x;
    const int cl = lane & 15, g = lane >> 4;

    if (w < 4) {
        // ========================= PRODUCER =========================
        // wave w streams rows 4w..4w+3, ONE 1KB load per row per round
        const int* stg = adj + ((size_t)(tile * 16 + w * 4)) * N_NODES + lane * 4;
        i32x4 ldA[4], ldB[4];

        auto issue = [&](i32x4 (&ld)[4], int c) {
            #pragma unroll
            for (int rr = 0; rr < 4; ++rr)
                ld[rr] = *(const i32x4*)(stg + (size_t)rr * N_NODES + c * SUBC);
        };
        auto pack = [&](i32x4 (&ld)[4], int c) {   // sub-chunk c -> buf[c&1]
            char* wbuf = bufs + (c & 1) * BUFSZ;
            #pragma unroll
            for (int rr = 0; rr < 4; ++rr) {
                i32x4 v = ld[rr];
                unsigned int d = (v[0] > 0 ? 1u : 0u) | (v[1] > 0 ? 0x100u : 0u)
                               | (v[2] > 0 ? 0x10000u : 0u) | (v[3] > 0 ? 0x1000000u : 0u);
                *(unsigned int*)(wbuf + (w * 4 + rr) * ROWPAD + lane * 4) = d;
            }
        };

        // prologue: A<-0, B<-1 in flight; pack(0)
        issue(ldA, 0);
        issue(ldB, 1);
        pack(ldA, 0);
        asm volatile("s_waitcnt lgkmcnt(0)" ::: "memory");
        __builtin_amdgcn_s_barrier();                    // B0 (prologue)

        for (int c = 0; c < NSUB; c += 2) {
            // even round c: issue(c+2)->A, pack(c+1) from B
            if (c + 2 < NSUB) issue(ldA, c + 2);
            __builtin_amdgcn_sched_barrier(0);
            pack(ldB, c + 1);
            __builtin_amdgcn_sched_barrier(0);
            asm volatile("s_waitcnt lgkmcnt(0)" ::: "memory");
            __builtin_amdgcn_s_barrier();                // end round c
            // odd round c+1: issue(c+3)->B, pack(c+2) from A
            if (c + 3 < NSUB) issue(ldB, c + 3);
            __builtin_amdgcn_sched_barrier(0);
            if (c + 2 < NSUB) pack(ldA, c + 2);
            __builtin_amdgcn_sched_barrier(0);
            asm volatile("s_waitcnt lgkmcnt(0)" ::: "memory");
            __builtin_amdgcn_s_barrier();                // end round c+1
        }

        __builtin_amdgcn_s_barrier();                    // wait consumers' red/zl
        // reduce 4 consumer partials, divide by Z, write out
        f32x4 rs = {0.f, 0.f, 0.f, 0.f};
        #pragma unroll
        for (int w2 = 0; w2 < 4; ++w2)
            rs += *(const f32x4*)(red + ((size_t)(w2 * 64 + lane)) * 16 + 4 * w);
        #pragma unroll
        for (int q = 0; q < 4; ++q) {
            const int rit = g * 4 + q;
            const float z = zl[rit] + zl[16 + rit] + zl[32 + rit] + zl[48 + rit];
            out[(size_t)(tile * 16 + rit) * OUT_FEAT + w * 16 + cl] = rs[q] / z;
        }
    } else {
        // ========================= CONSUMER =========================
        const int cw  = w - 4;
        const int row = tile * 16 + cl;
        const float s1r = s1v[row];

        f32x4 acc0 = {0.f, 0.f, 0.f, 0.f};
        f32x4 acc1 = acc0, acc2 = acc0, acc3 = acc0;
        float zacc = 0.f;

        __builtin_amdgcn_s_barrier();                    // B0 (prologue)

        for (int c = 0; c < NSUB; ++c) {
            const char* rbuf = bufs + (c & 1) * BUFSZ;
            #pragma unroll
            for (int kk = 0; kk < KPW; ++kk) {
                const int ks = cw * KPW + kk;            // k-step in sub (0..7)
                const uint2 ab = *(const uint2*)(rbuf + cl * ROWPAD + ks * 32 + 8 * g);
                const float* sp = s2v + c * SUBC + ks * 32 + 8 * g;   // L2-hot
                const f32x4 s0  = *(const f32x4*)(sp);
                const f32x4 s1x = *(const f32x4*)(sp + 4);

                bf16x8 af;
                #pragma unroll
                for (int e = 0; e < 4; ++e) {
                    float tv = s1r + s0[e];
                    float el = fmaxf(tv, NEG_SLOPE * tv);
                    float wv = ((ab.x >> (8 * e)) & 1u) ? exp2_fast(el) : 1.0f;
                    zacc += wv;
                    af[e] = f2bf_fast(wv);
                }
                #pragma unroll
                for (int e = 0; e < 4; ++e) {
                    float tv = s1r + s1x[e];
                    float el = fmaxf(tv, NEG_SLOPE * tv);
                    float wv = ((ab.y >> (8 * e)) & 1u) ? exp2_fast(el) : 1.0f;
                    zacc += wv;
                    af[4 + e] = f2bf_fast(wv);
                }

                // B-fragments 2+2 to cap live VGPRs under the (512,8) budget
                const unsigned short* wq = whb + ((size_t)(c * 8 + ks)) * 2048 + lane * 8;
                {
                    bf16x8 B0 = *(const bf16x8*)(wq);
                    bf16x8 B1 = *(const bf16x8*)(wq + 512);
                    acc0 = __builtin_amdgcn_mfma_f32_16x16x32_bf16(af, B0, acc0, 0, 0, 0);
                    acc1 = __builtin_amdgcn_mfma_f32_16x16x32_bf16(af, B1, acc1, 0, 0, 0);
                }
                {
                    bf16x8 B2 = *(const bf16x8*)(wq + 1024);
                    bf16x8 B3 = *(const bf16x8*)(wq + 1536);
                    acc2 = __builtin_amdgcn_mfma_f32_16x16x32_bf16(af, B2, acc2, 0, 0, 0);
                    acc3 = __builtin_amdgcn_mfma_f32_16x16x32_bf16(af, B3, acc3, 0, 0, 0);
                }
            }
            asm volatile("s_waitcnt lgkmcnt(0)" ::: "memory");
            __builtin_amdgcn_s_barrier();                // end round c
        }

        // publish partials
        *(f32x4*)(red + ((size_t)(cw * 64 + lane)) * 16 + 0)  = acc0;
        *(f32x4*)(red + ((size_t)(cw * 64 + lane)) * 16 + 4)  = acc1;
        *(f32x4*)(red + ((size_t)(cw * 64 + lane)) * 16 + 8)  = acc2;
        *(f32x4*)(red + ((size_t)(cw * 64 + lane)) * 16 + 12) = acc3;
        float zz = zacc + __shfl_xor(zacc, 16);
        zz += __shfl_xor(zz, 32);
        if (lane < 16) zl[cw * 16 + lane] = zz;
        asm volatile("s_waitcnt lgkmcnt(0)" ::: "memory");
        __builtin_amdgcn_s_barrier();                    // release producers
    }
}

// ---------------------------------------------------------------------------
extern "C" void kernel_launch(void* const* d_in, const int* in_sizes, int n_in,
                              void* d_out, int out_size, void* d_ws, size_t ws_size,
                              hipStream_t stream) {
    const float* x   = (const float*)d_in[0];
    const int*   adj = (const int*)d_in[1];
    const float* W   = (const float*)d_in[2];
    const float* a   = (const float*)d_in[3];
    float* out = (float*)d_out;

    char* ws = (char*)d_ws;
    float* s1 = (float*)(ws);                                  // 32 KB
    float* s2 = (float*)(ws + 32 * 1024);                      // 32 KB
    unsigned short* whb = (unsigned short*)(ws + 64 * 1024);   // 1 MB

    k_wh   <<<dim3(N_NODES / 4), dim3(256), 0, stream>>>(x, W, a, s1, s2, whb);
    k_fused<<<dim3(TILES), dim3(512), 0, stream>>>(adj, s1, s2, whb, out);
}